// Round 1
// baseline (298.510 us; speedup 1.0000x reference)
//
#include <hip/hip_runtime.h>

#define BSZ 32
#define NN 512
#define INF 256
#define OUTF 128
#define NH 4
#define HD (NH*OUTF)       // 512
#define NEG_SLOPE 0.2f

#define TIP 16             // rows per block, projection
#define TIA 8              // rows per block, attention

// ---------------- Kernel 1: h = x @ w, plus per-head coeffs ----------------
__global__ __launch_bounds__(256) void k_project(
    const float* __restrict__ x, const float* __restrict__ w,
    const float* __restrict__ ai, const float* __restrict__ aj,
    float* __restrict__ hbuf, float* __restrict__ ci, float* __restrict__ cj)
{
    __shared__ float xs[TIP][INF];    // 16 KB
    const int tid = threadIdx.x;
    const int row0 = blockIdx.x * TIP;

    // stage x rows: TIP*INF = 4096 floats = 1024 float4, 256 threads -> 4 each
    const float4* xsrc = (const float4*)(x + (size_t)row0 * INF);
    float4* xdst = (float4*)&xs[0][0];
    #pragma unroll
    for (int idx = 0; idx < 4; ++idx)
        xdst[tid + idx*256] = xsrc[tid + idx*256];
    __syncthreads();

    const int col2 = tid * 2;
    float2 acc[TIP];
    #pragma unroll
    for (int r = 0; r < TIP; ++r) acc[r] = make_float2(0.f, 0.f);

    for (int k = 0; k < INF; k += 4) {
        const float2 wv0 = *(const float2*)&w[(k+0)*HD + col2];
        const float2 wv1 = *(const float2*)&w[(k+1)*HD + col2];
        const float2 wv2 = *(const float2*)&w[(k+2)*HD + col2];
        const float2 wv3 = *(const float2*)&w[(k+3)*HD + col2];
        #pragma unroll
        for (int r = 0; r < TIP; ++r) {
            const float4 xv = *(const float4*)&xs[r][k];
            acc[r].x = fmaf(xv.x, wv0.x, acc[r].x);
            acc[r].y = fmaf(xv.x, wv0.y, acc[r].y);
            acc[r].x = fmaf(xv.y, wv1.x, acc[r].x);
            acc[r].y = fmaf(xv.y, wv1.y, acc[r].y);
            acc[r].x = fmaf(xv.z, wv2.x, acc[r].x);
            acc[r].y = fmaf(xv.z, wv2.y, acc[r].y);
            acc[r].x = fmaf(xv.w, wv3.x, acc[r].x);
            acc[r].y = fmaf(xv.w, wv3.y, acc[r].y);
        }
    }

    const float2 aiv = *(const float2*)&ai[col2];
    const float2 ajv = *(const float2*)&aj[col2];
    const int head = tid >> 6;   // wave index == head (128 cols per head, 2/thread)
    #pragma unroll
    for (int r = 0; r < TIP; ++r) {
        *(float2*)&hbuf[(size_t)(row0 + r)*HD + col2] = acc[r];
        float pi = acc[r].x*aiv.x + acc[r].y*aiv.y;
        float pj = acc[r].x*ajv.x + acc[r].y*ajv.y;
        #pragma unroll
        for (int off = 32; off; off >>= 1) {
            pi += __shfl_down(pi, off);
            pj += __shfl_down(pj, off);
        }
        if ((tid & 63) == 0) {
            ci[(row0 + r)*NH + head] = pi;
            cj[(row0 + r)*NH + head] = pj;
        }
    }
}

// ------------- Kernel 2: masked softmax attention + aggregation -------------
__global__ __launch_bounds__(256) void k_attn(
    const float* __restrict__ adj, const float* __restrict__ hbuf,
    const float* __restrict__ ci, const float* __restrict__ cj,
    const float* __restrict__ bias, float* __restrict__ out)
{
    __shared__ float att_s[NH*NN*TIA];   // [(h*NN + j)*TIA + r]  -> 64 KB
    __shared__ float ci_s[TIA][NH];
    __shared__ float redm[4][NH];
    __shared__ float redsum[4][NH];

    const int tid = threadIdx.x;
    const int b  = blockIdx.x >> 6;          // NN/TIA = 64 tiles per batch
    const int i0 = (blockIdx.x & 63) * TIA;

    if (tid < TIA*NH) {
        const int r = tid >> 2, hh = tid & 3;
        ci_s[r][hh] = ci[(b*NN + i0 + r)*NH + hh];
    }
    const int j0 = tid, j1 = tid + 256;
    const float4 cjv0 = *(const float4*)&cj[(b*NN + j0)*NH];
    const float4 cjv1 = *(const float4*)&cj[(b*NN + j1)*NH];
    const int wave = tid >> 6;
    __syncthreads();

    const float* adj_b = adj + (size_t)(b*NN + i0)*NN;
    for (int r = 0; r < TIA; ++r) {
        const float a0 = adj_b[r*NN + j0];
        const float a1 = adj_b[r*NN + j1];
        float e0[NH], e1[NH], mh[NH];
        #pragma unroll
        for (int hh = 0; hh < NH; ++hh) {
            const float c = ci_s[r][hh];
            float s0 = c + ((const float*)&cjv0)[hh];
            s0 = s0 > 0.f ? s0 : NEG_SLOPE*s0;
            e0[hh] = (a0 > 0.f) ? s0 : -1e9f;
            float s1 = c + ((const float*)&cjv1)[hh];
            s1 = s1 > 0.f ? s1 : NEG_SLOPE*s1;
            e1[hh] = (a1 > 0.f) ? s1 : -1e9f;
            mh[hh] = fmaxf(e0[hh], e1[hh]);
        }
        #pragma unroll
        for (int off = 32; off; off >>= 1) {
            #pragma unroll
            for (int hh = 0; hh < NH; ++hh)
                mh[hh] = fmaxf(mh[hh], __shfl_down(mh[hh], off));
        }
        if ((tid & 63) == 0) {
            #pragma unroll
            for (int hh = 0; hh < NH; ++hh) redm[wave][hh] = mh[hh];
        }
        __syncthreads();
        float sh[NH];
        #pragma unroll
        for (int hh = 0; hh < NH; ++hh) {
            const float m = fmaxf(fmaxf(redm[0][hh], redm[1][hh]),
                                  fmaxf(redm[2][hh], redm[3][hh]));
            e0[hh] = __expf(e0[hh] - m);   // masked: exp(-1e9 - m) -> 0, matches ref
            e1[hh] = __expf(e1[hh] - m);
            sh[hh] = e0[hh] + e1[hh];
        }
        #pragma unroll
        for (int off = 32; off; off >>= 1) {
            #pragma unroll
            for (int hh = 0; hh < NH; ++hh)
                sh[hh] += __shfl_down(sh[hh], off);
        }
        if ((tid & 63) == 0) {
            #pragma unroll
            for (int hh = 0; hh < NH; ++hh) redsum[wave][hh] = sh[hh];
        }
        __syncthreads();
        #pragma unroll
        for (int hh = 0; hh < NH; ++hh) {
            const float s = redsum[0][hh]+redsum[1][hh]+redsum[2][hh]+redsum[3][hh];
            const float inv = 1.0f / s;
            att_s[(hh*NN + j0)*TIA + r] = e0[hh] * inv * a0;  // re-mask (* adj)
            att_s[(hh*NN + j1)*TIA + r] = e1[hh] * inv * a1;
        }
    }
    __syncthreads();

    // phase 2: out[i0+r, col] = sum_j att[r][h][j] * h[b,j,col]
    const int col2 = tid * 2;
    const int head = tid >> 6;           // wave-uniform -> LDS broadcast reads
    float2 acc[TIA];
    #pragma unroll
    for (int r = 0; r < TIA; ++r) acc[r] = make_float2(0.f, 0.f);

    const float* hb = hbuf + (size_t)b*NN*HD + col2;
    const float* ap_base = &att_s[head*NN*TIA];
    for (int j = 0; j < NN; ++j) {
        const float2 hv = *(const float2*)(hb + (size_t)j*HD);
        const float4 av0 = *(const float4*)(ap_base + j*TIA);
        const float4 av1 = *(const float4*)(ap_base + j*TIA + 4);
        acc[0].x = fmaf(av0.x, hv.x, acc[0].x); acc[0].y = fmaf(av0.x, hv.y, acc[0].y);
        acc[1].x = fmaf(av0.y, hv.x, acc[1].x); acc[1].y = fmaf(av0.y, hv.y, acc[1].y);
        acc[2].x = fmaf(av0.z, hv.x, acc[2].x); acc[2].y = fmaf(av0.z, hv.y, acc[2].y);
        acc[3].x = fmaf(av0.w, hv.x, acc[3].x); acc[3].y = fmaf(av0.w, hv.y, acc[3].y);
        acc[4].x = fmaf(av1.x, hv.x, acc[4].x); acc[4].y = fmaf(av1.x, hv.y, acc[4].y);
        acc[5].x = fmaf(av1.y, hv.x, acc[5].x); acc[5].y = fmaf(av1.y, hv.y, acc[5].y);
        acc[6].x = fmaf(av1.z, hv.x, acc[6].x); acc[6].y = fmaf(av1.z, hv.y, acc[6].y);
        acc[7].x = fmaf(av1.w, hv.x, acc[7].x); acc[7].y = fmaf(av1.w, hv.y, acc[7].y);
    }
    const float2 bv = *(const float2*)&bias[col2];
    #pragma unroll
    for (int r = 0; r < TIA; ++r) {
        float2 o; o.x = acc[r].x + bv.x; o.y = acc[r].y + bv.y;
        *(float2*)&out[(size_t)(b*NN + i0 + r)*HD + col2] = o;
    }
}

extern "C" void kernel_launch(void* const* d_in, const int* in_sizes, int n_in,
                              void* d_out, int out_size, void* d_ws, size_t ws_size,
                              hipStream_t stream)
{
    const float* x    = (const float*)d_in[0];
    const float* adj  = (const float*)d_in[1];
    const float* w    = (const float*)d_in[2];
    const float* ai   = (const float*)d_in[3];
    const float* aj   = (const float*)d_in[4];
    const float* bias = (const float*)d_in[5];
    float* out = (float*)d_out;

    float* hbuf = (float*)d_ws;                        // BSZ*NN*HD floats
    float* ci   = hbuf + (size_t)BSZ*NN*HD;            // BSZ*NN*NH
    float* cj   = ci   + (size_t)BSZ*NN*NH;            // BSZ*NN*NH

    k_project<<<BSZ*NN/TIP, 256, 0, stream>>>(x, w, ai, aj, hbuf, ci, cj);
    k_attn<<<BSZ*(NN/TIA), 256, 0, stream>>>(adj, hbuf, ci, cj, bias, out);
}

// Round 2
// 85.252 us; speedup vs baseline: 3.5015x; 3.5015x over previous
//
#include <hip/hip_runtime.h>

#define BSZ 32
#define NN 512
#define INF 256
#define OUTF 128
#define NH 4
#define HD 512
#define NEG_SLOPE 0.2f

typedef __attribute__((ext_vector_type(8))) short bf16x8;
typedef __attribute__((ext_vector_type(8))) unsigned short ushort8;
typedef __attribute__((ext_vector_type(4))) float f32x4;

static __device__ __forceinline__ unsigned short f2bf(float f) {
    unsigned u = __builtin_bit_cast(unsigned, f);
    return (unsigned short)((u + 0x7FFFu + ((u >> 16) & 1u)) >> 16);
}

// ---- pack x -> bf16 row-major [16384][256] ----
__global__ __launch_bounds__(256) void kpack_x(const float* __restrict__ x,
                                               unsigned short* __restrict__ xb) {
    int gid = blockIdx.x * 256 + threadIdx.x;          // 8 elems each
    const float4* xv = (const float4*)x;
    float4 a = xv[gid * 2], b = xv[gid * 2 + 1];
    ushort8 o;
    o[0]=f2bf(a.x); o[1]=f2bf(a.y); o[2]=f2bf(a.z); o[3]=f2bf(a.w);
    o[4]=f2bf(b.x); o[5]=f2bf(b.y); o[6]=f2bf(b.z); o[7]=f2bf(b.w);
    *(ushort8*)(xb + (size_t)gid * 8) = o;
}

// ---- pack w[256][512] -> wB frag layout ((kb*4+g)*512 + c)*8 + e, k=kb*32+g*8+e ----
__global__ __launch_bounds__(256) void kpack_w(const float* __restrict__ w,
                                               unsigned short* __restrict__ wB) {
    int gid = blockIdx.x * 256 + threadIdx.x;          // 131072 total
    int c = gid & 511, k = gid >> 9;
    int kb = k >> 5, g = (k >> 3) & 3, e = k & 7;
    wB[(((size_t)(kb * 4 + g) * 512) + c) * 8 + e] = f2bf(w[(size_t)k * 512 + c]);
}

// ---- projection GEMM (MFMA) + coeffs + hB frag-layout store ----
__global__ __launch_bounds__(256) void k_proj(
    const unsigned short* __restrict__ xb, const unsigned short* __restrict__ wB,
    const float* __restrict__ ai, const float* __restrict__ aj,
    unsigned short* __restrict__ hB, float* __restrict__ ci, float* __restrict__ cj)
{
    const int tid = threadIdx.x;
    const int lane = tid & 63, head = tid >> 6;
    const int l15 = lane & 15, g = lane >> 4;
    const int row0 = blockIdx.x * 32;                  // global row = b*512 + nloc

    f32x4 acc[2][8] = {};
    const unsigned short* ap0 = xb + (size_t)(row0 + l15) * INF + g * 8;
    const unsigned short* ap1 = ap0 + 16 * INF;
    const unsigned short* bp  = wB + ((size_t)g * 512 + head * 128 + l15) * 8;

    #pragma unroll
    for (int kb = 0; kb < 8; ++kb) {
        bf16x8 a0 = *(const bf16x8*)(ap0 + kb * 32);
        bf16x8 a1 = *(const bf16x8*)(ap1 + kb * 32);
        #pragma unroll
        for (int nf = 0; nf < 8; ++nf) {
            bf16x8 bv = *(const bf16x8*)(bp + (size_t)kb * 16384 + nf * 128);
            acc[0][nf] = __builtin_amdgcn_mfma_f32_16x16x32_bf16(a0, bv, acc[0][nf], 0, 0, 0);
            acc[1][nf] = __builtin_amdgcn_mfma_f32_16x16x32_bf16(a1, bv, acc[1][nf], 0, 0, 0);
        }
    }

    float aiv[8], ajv[8];
    #pragma unroll
    for (int nf = 0; nf < 8; ++nf) {
        aiv[nf] = ai[head * 128 + nf * 16 + l15];
        ajv[nf] = aj[head * 128 + nf * 16 + l15];
    }
    const int b = row0 >> 9;
    const int nloc0 = row0 & 511;

    #pragma unroll
    for (int m = 0; m < 2; ++m) {
        float pi[4] = {0,0,0,0}, pj[4] = {0,0,0,0};
        #pragma unroll
        for (int nf = 0; nf < 8; ++nf)
            #pragma unroll
            for (int reg = 0; reg < 4; ++reg) {
                pi[reg] = fmaf(acc[m][nf][reg], aiv[nf], pi[reg]);
                pj[reg] = fmaf(acc[m][nf][reg], ajv[nf], pj[reg]);
            }
        #pragma unroll
        for (int reg = 0; reg < 4; ++reg) {
            #pragma unroll
            for (int off = 1; off < 16; off <<= 1) {
                pi[reg] += __shfl_xor(pi[reg], off);
                pj[reg] += __shfl_xor(pj[reg], off);
            }
        }
        if (l15 == 0) {
            #pragma unroll
            for (int reg = 0; reg < 4; ++reg) {
                int n = nloc0 + 16 * m + 4 * g + reg;   // D row = g*4+reg
                ci[((size_t)(b * NN + n)) * 4 + head] = pi[reg];
                cj[((size_t)(b * NN + n)) * 4 + head] = pj[reg];
            }
        }
        // hB[(((bh*16+kb2)*4+g2)*128+dd)*8+e], j=n
        #pragma unroll
        for (int reg = 0; reg < 4; ++reg) {
            int n = nloc0 + 16 * m + 4 * g + reg;
            int kb2 = n >> 5, g2 = (n >> 3) & 3, e = n & 7;
            size_t base = ((((size_t)(b * 4 + head) * 16 + kb2) * 4 + g2) * 128) * 8 + e;
            #pragma unroll
            for (int nf = 0; nf < 8; ++nf)
                hB[base + (size_t)(nf * 16 + l15) * 8] = f2bf(acc[m][nf][reg]);
        }
    }
}

// ---- fused masked-softmax attention + MFMA aggregation ----
__global__ __launch_bounds__(256) void k_attn(
    const float* __restrict__ adj, const unsigned short* __restrict__ hB,
    const float* __restrict__ ci, const float* __restrict__ cj,
    const float* __restrict__ bias, float* __restrict__ out)
{
    __shared__ float cj_s[NH][NN];
    __shared__ float ci_s[NH][16];
    __shared__ unsigned long long mask_s[16][8];
    __shared__ float m_s[NH][16], is_s[NH][16];

    const int tid = threadIdx.x;
    const int lane = tid & 63, h = tid >> 6;
    const int b = blockIdx.x >> 5;
    const int i0 = (blockIdx.x & 31) * 16;

    #pragma unroll
    for (int it = 0; it < 2; ++it) {
        int n = tid + it * 256;
        float4 v = *(const float4*)&cj[(size_t)(b * NN + n) * 4];
        cj_s[0][n] = v.x; cj_s[1][n] = v.y; cj_s[2][n] = v.z; cj_s[3][n] = v.w;
    }
    if (tid < 64) {
        int r = tid >> 2, hh = tid & 3;
        ci_s[hh][r] = ci[(size_t)(b * NN + i0 + r) * 4 + hh];
    }
    #pragma unroll
    for (int rr = 0; rr < 4; ++rr) {
        int r = h * 4 + rr;
        const float* arow = adj + (size_t)(b * NN + i0 + r) * NN;
        #pragma unroll
        for (int t = 0; t < 8; ++t) {
            unsigned long long msk = __ballot(arow[t * 64 + lane] > 0.f);
            if (lane == 0) mask_s[r][t] = msk;
        }
    }
    __syncthreads();

    // per-row max & inv-sum (head h = this wave)
    for (int r = 0; r < 16; ++r) {
        float base = ci_s[h][r];
        float mv = -1e30f;
        #pragma unroll
        for (int t = 0; t < 8; ++t) {
            float sc = base + cj_s[h][t * 64 + lane];
            sc = sc > 0.f ? sc : NEG_SLOPE * sc;
            unsigned bit = (unsigned)((mask_s[r][t] >> lane) & 1ull);
            mv = bit ? fmaxf(mv, sc) : mv;
        }
        #pragma unroll
        for (int off = 32; off; off >>= 1) mv = fmaxf(mv, __shfl_xor(mv, off));
        float sv = 0.f;
        #pragma unroll
        for (int t = 0; t < 8; ++t) {
            float sc = base + cj_s[h][t * 64 + lane];
            sc = sc > 0.f ? sc : NEG_SLOPE * sc;
            unsigned bit = (unsigned)((mask_s[r][t] >> lane) & 1ull);
            float p = __expf(sc - mv);
            sv += bit ? p : 0.f;
        }
        #pragma unroll
        for (int off = 32; off; off >>= 1) sv += __shfl_xor(sv, off);
        if (lane == 0) { m_s[h][r] = mv; is_s[h][r] = sv > 0.f ? 1.f / sv : 0.f; }
    }
    __syncthreads();

    const int l15 = lane & 15, g = lane >> 4;
    const float rm = m_s[h][l15], rinv = is_s[h][l15], rci = ci_s[h][l15];
    const unsigned long long* mrow = mask_s[l15];

    f32x4 acc[8] = {};
    const unsigned short* hb = hB + (size_t)(b * 4 + h) * 65536 + g * 1024 + l15 * 8;

    for (int kb = 0; kb < 16; ++kb) {
        int j0 = kb * 32 + g * 8;
        float4 c0 = *(const float4*)&cj_s[h][j0];
        float4 c1 = *(const float4*)&cj_s[h][j0 + 4];
        float cjv[8] = {c0.x, c0.y, c0.z, c0.w, c1.x, c1.y, c1.z, c1.w};
        unsigned bits = (unsigned)((mrow[j0 >> 6] >> (j0 & 63)) & 0xFFull);
        unsigned short af[8];
        #pragma unroll
        for (int e = 0; e < 8; ++e) {
            float sc = rci + cjv[e];
            sc = sc > 0.f ? sc : NEG_SLOPE * sc;
            float p = __expf(sc - rm) * rinv;
            p = ((bits >> e) & 1u) ? p : 0.f;
            af[e] = f2bf(p);
        }
        bf16x8 avec = *(bf16x8*)af;
        const unsigned short* hp = hb + kb * 4096;
        #pragma unroll
        for (int nf = 0; nf < 8; ++nf) {
            bf16x8 bv = *(const bf16x8*)(hp + nf * 128);
            acc[nf] = __builtin_amdgcn_mfma_f32_16x16x32_bf16(avec, bv, acc[nf], 0, 0, 0);
        }
    }

    #pragma unroll
    for (int nf = 0; nf < 8; ++nf) {
        int colg = h * 128 + nf * 16 + l15;
        float bv = bias[colg];
        #pragma unroll
        for (int reg = 0; reg < 4; ++reg) {
            int i = g * 4 + reg;                        // D row
            out[(size_t)(b * NN + i0 + i) * HD + colg] = acc[nf][reg] + bv;
        }
    }
}

extern "C" void kernel_launch(void* const* d_in, const int* in_sizes, int n_in,
                              void* d_out, int out_size, void* d_ws, size_t ws_size,
                              hipStream_t stream)
{
    const float* x    = (const float*)d_in[0];
    const float* adj  = (const float*)d_in[1];
    const float* w    = (const float*)d_in[2];
    const float* ai   = (const float*)d_in[3];
    const float* aj   = (const float*)d_in[4];
    const float* bias = (const float*)d_in[5];
    float* out = (float*)d_out;

    char* ws = (char*)d_ws;
    unsigned short* xb = (unsigned short*)ws;                       // 8,388,608 B
    unsigned short* wB = (unsigned short*)(ws + 8388608);           //   262,144 B
    unsigned short* hB = (unsigned short*)(ws + 8650752);           // 16,777,216 B
    float* ci          = (float*)(ws + 25427968);                   //   262,144 B
    float* cj          = (float*)(ws + 25690112);                   //   262,144 B

    kpack_x<<<2048, 256, 0, stream>>>(x, xb);
    kpack_w<<<512, 256, 0, stream>>>(w, wB);
    k_proj<<<BSZ * NN / 32, 256, 0, stream>>>(xb, wB, ai, aj, hB, ci, cj);
    k_attn<<<BSZ * (NN / 16), 256, 0, stream>>>(adj, hB, ci, cj, bias, out);
}

// Round 3
// 80.497 us; speedup vs baseline: 3.7083x; 1.0591x over previous
//
#include <hip/hip_runtime.h>

#define BSZ 32
#define NN 512
#define INF 256
#define OUTF 128
#define NH 4
#define HD 512
#define NEG_SLOPE 0.2f

typedef __attribute__((ext_vector_type(8))) short bf16x8;
typedef __attribute__((ext_vector_type(8))) unsigned short ushort8;
typedef __attribute__((ext_vector_type(4))) float f32x4;

static __device__ __forceinline__ unsigned short f2bf(float f) {
    unsigned u = __builtin_bit_cast(unsigned, f);
    return (unsigned short)((u + 0x7FFFu + ((u >> 16) & 1u)) >> 16);
}

// ---- pack x -> bf16 row-major [16384][256] ----
__global__ __launch_bounds__(256) void kpack_x(const float* __restrict__ x,
                                               unsigned short* __restrict__ xb) {
    int gid = blockIdx.x * 256 + threadIdx.x;          // 8 elems each
    const float4* xv = (const float4*)x;
    float4 a = xv[gid * 2], b = xv[gid * 2 + 1];
    ushort8 o;
    o[0]=f2bf(a.x); o[1]=f2bf(a.y); o[2]=f2bf(a.z); o[3]=f2bf(a.w);
    o[4]=f2bf(b.x); o[5]=f2bf(b.y); o[6]=f2bf(b.z); o[7]=f2bf(b.w);
    *(ushort8*)(xb + (size_t)gid * 8) = o;
}

// ---- pack w[256][512] -> wB frag layout ((kb*4+g)*512 + c)*8 + e, k=kb*32+g*8+e ----
__global__ __launch_bounds__(256) void kpack_w(const float* __restrict__ w,
                                               unsigned short* __restrict__ wB) {
    int gid = blockIdx.x * 256 + threadIdx.x;          // 131072 total
    int c = gid & 511, k = gid >> 9;
    int kb = k >> 5, g = (k >> 3) & 3, e = k & 7;
    wB[(((size_t)(kb * 4 + g) * 512) + c) * 8 + e] = f2bf(w[(size_t)k * 512 + c]);
}

// ---- projection GEMM (MFMA) + coeffs + hB frag-layout store ----
__global__ __launch_bounds__(256) void k_proj(
    const unsigned short* __restrict__ xb, const unsigned short* __restrict__ wB,
    const float* __restrict__ ai, const float* __restrict__ aj,
    unsigned short* __restrict__ hB, float* __restrict__ ci, float* __restrict__ cj)
{
    const int tid = threadIdx.x;
    const int lane = tid & 63, head = tid >> 6;
    const int l15 = lane & 15, g = lane >> 4;
    const int row0 = blockIdx.x * 32;                  // global row = b*512 + nloc

    f32x4 acc[2][8] = {};
    const unsigned short* ap0 = xb + (size_t)(row0 + l15) * INF + g * 8;
    const unsigned short* ap1 = ap0 + 16 * INF;
    const unsigned short* bp  = wB + ((size_t)g * 512 + head * 128 + l15) * 8;

    #pragma unroll
    for (int kb = 0; kb < 8; ++kb) {
        bf16x8 a0 = *(const bf16x8*)(ap0 + kb * 32);
        bf16x8 a1 = *(const bf16x8*)(ap1 + kb * 32);
        #pragma unroll
        for (int nf = 0; nf < 8; ++nf) {
            bf16x8 bv = *(const bf16x8*)(bp + (size_t)kb * 16384 + nf * 128);
            acc[0][nf] = __builtin_amdgcn_mfma_f32_16x16x32_bf16(a0, bv, acc[0][nf], 0, 0, 0);
            acc[1][nf] = __builtin_amdgcn_mfma_f32_16x16x32_bf16(a1, bv, acc[1][nf], 0, 0, 0);
        }
    }

    float aiv[8], ajv[8];
    #pragma unroll
    for (int nf = 0; nf < 8; ++nf) {
        aiv[nf] = ai[head * 128 + nf * 16 + l15];
        ajv[nf] = aj[head * 128 + nf * 16 + l15];
    }
    const int b = row0 >> 9;
    const int nloc0 = row0 & 511;

    #pragma unroll
    for (int m = 0; m < 2; ++m) {
        float pi[4] = {0,0,0,0}, pj[4] = {0,0,0,0};
        #pragma unroll
        for (int nf = 0; nf < 8; ++nf)
            #pragma unroll
            for (int reg = 0; reg < 4; ++reg) {
                pi[reg] = fmaf(acc[m][nf][reg], aiv[nf], pi[reg]);
                pj[reg] = fmaf(acc[m][nf][reg], ajv[nf], pj[reg]);
            }
        #pragma unroll
        for (int reg = 0; reg < 4; ++reg) {
            #pragma unroll
            for (int off = 1; off < 16; off <<= 1) {
                pi[reg] += __shfl_xor(pi[reg], off);
                pj[reg] += __shfl_xor(pj[reg], off);
            }
        }
        if (l15 == 0) {
            #pragma unroll
            for (int reg = 0; reg < 4; ++reg) {
                int n = nloc0 + 16 * m + 4 * g + reg;   // D row = g*4+reg
                ci[((size_t)(b * NN + n)) * 4 + head] = pi[reg];
                cj[((size_t)(b * NN + n)) * 4 + head] = pj[reg];
            }
        }
        // hB[(((bh*16+kb2)*4+g2)*128+dd)*8+e], j=n
        #pragma unroll
        for (int reg = 0; reg < 4; ++reg) {
            int n = nloc0 + 16 * m + 4 * g + reg;
            int kb2 = n >> 5, g2 = (n >> 3) & 3, e = n & 7;
            size_t base = ((((size_t)(b * 4 + head) * 16 + kb2) * 4 + g2) * 128) * 8 + e;
            #pragma unroll
            for (int nf = 0; nf < 8; ++nf)
                hB[base + (size_t)(nf * 16 + l15) * 8] = f2bf(acc[m][nf][reg]);
        }
    }
}

// ---- fused masked-softmax attention + MFMA aggregation ----
// 512 threads: wave = (head<<1)|sub. Single-exp, unnormalized-p bf16 A-frags
// in swizzled LDS; 1/sum folded into epilogue.
__global__ __launch_bounds__(512) void k_attn(
    const float* __restrict__ adj, const unsigned short* __restrict__ hB,
    const float* __restrict__ ci, const float* __restrict__ cj,
    const float* __restrict__ bias, float* __restrict__ out)
{
    __shared__ __align__(16) float cj_s[NH][NN];            // 8 KB
    __shared__ float ci_s[NH][16];
    __shared__ unsigned long long mask_s[16][8];            // 1 KB
    __shared__ float is_s[NH][16];
    __shared__ __align__(16) unsigned short att_s[NH*16*NN]; // 64 KB, swizzled

    const int tid = threadIdx.x;
    const int lane = tid & 63, wave = tid >> 6;
    const int h = wave >> 1, sub = wave & 1;

    // XCD swizzle: hw id round-robins across 8 XCDs; give XCD x logical
    // blocks [x*128, x*128+128) = batches {4x..4x+3} so each b's 512 KB hB
    // slab is L2-resident across its 32 i-tiles. 1024 % 8 == 0 -> bijective.
    const int orig = blockIdx.x;
    const int swz = (orig & 7) * 128 + (orig >> 3);
    const int b = swz >> 5;
    const int i0 = (swz & 31) * 16;

    {   // cj -> LDS, transposed per head
        int n = tid;
        float4 v = *(const float4*)&cj[(size_t)(b * NN + n) * 4];
        cj_s[0][n] = v.x; cj_s[1][n] = v.y; cj_s[2][n] = v.z; cj_s[3][n] = v.w;
    }
    if (tid < 64) {
        int r = tid >> 2, hh = tid & 3;
        ci_s[hh][r] = ci[(size_t)(b * NN + i0 + r) * 4 + hh];
    }
    // adjacency -> ballot bitmasks (head-independent, built once)
    #pragma unroll
    for (int rr = 0; rr < 2; ++rr) {
        int r = wave * 2 + rr;
        const float* arow = adj + (size_t)(b * NN + i0 + r) * NN;
        #pragma unroll
        for (int t = 0; t < 8; ++t) {
            unsigned long long msk = __ballot(arow[t * 64 + lane] > 0.f);
            if (lane == 0) mask_s[r][t] = msk;
        }
    }
    __syncthreads();

    // ---- phase 1: per-row masked max (of cj; leaky is monotone) + exp + store
    const int r0 = sub * 8;
    for (int rr = 0; rr < 8; ++rr) {
        const int r = r0 + rr;
        const unsigned long long* mrow = mask_s[r];
        const float basec = ci_s[h][r];
        float mv = -1e30f;
        #pragma unroll
        for (int c = 0; c < 4; ++c) {
            int j2 = c * 128 + lane * 2;
            float2 cv = *(const float2*)&cj_s[h][j2];
            unsigned bb = (unsigned)((mrow[j2 >> 6] >> (j2 & 63)) & 3ull);
            if (bb & 1u) mv = fmaxf(mv, cv.x);
            if (bb & 2u) mv = fmaxf(mv, cv.y);
        }
        #pragma unroll
        for (int off = 32; off; off >>= 1) mv = fmaxf(mv, __shfl_xor(mv, off));
        float sm = basec + mv;
        const float m = sm > 0.f ? sm : NEG_SLOPE * sm;   // row max of leaky scores

        float sv = 0.f;
        char* abase = ((char*)att_s) + h * 16384 + r * 1024;
        const int rx = (r & 7) << 4;
        #pragma unroll
        for (int c = 0; c < 4; ++c) {
            int j2 = c * 128 + lane * 2;
            float2 cv = *(const float2*)&cj_s[h][j2];
            unsigned bb = (unsigned)((mrow[j2 >> 6] >> (j2 & 63)) & 3ull);
            float s0 = basec + cv.x; s0 = s0 > 0.f ? s0 : NEG_SLOPE * s0;
            float s1 = basec + cv.y; s1 = s1 > 0.f ? s1 : NEG_SLOPE * s1;
            float p0 = __expf(s0 - m); p0 = (bb & 1u) ? p0 : 0.f;
            float p1 = __expf(s1 - m); p1 = (bb & 2u) ? p1 : 0.f;
            sv += p0 + p1;
            unsigned pk = (unsigned)f2bf(p0) | ((unsigned)f2bf(p1) << 16);
            *(unsigned*)(abase + ((j2 * 2) ^ rx)) = pk;
        }
        #pragma unroll
        for (int off = 32; off; off >>= 1) sv += __shfl_xor(sv, off);
        if (lane == 0) is_s[h][r] = sv > 0.f ? 1.f / sv : 0.f;
    }
    __syncthreads();

    // ---- phase 2: pure MFMA aggregation, wave covers nf = sub*4 .. +3
    const int l15 = lane & 15, g = lane >> 4;
    f32x4 acc4[4] = {};
    const unsigned short* hbp = hB + (size_t)(b * 4 + h) * 65536
                                   + g * 1024 + sub * 512 + l15 * 8;
    const char* ab = ((const char*)att_s) + h * 16384 + l15 * 1024;
    const int rx2 = (l15 & 7) << 4;

    #pragma unroll
    for (int kb = 0; kb < 16; ++kb) {
        bf16x8 av = *(const bf16x8*)(ab + ((kb * 64 + g * 16) ^ rx2));
        #pragma unroll
        for (int nfl = 0; nfl < 4; ++nfl) {
            bf16x8 bv = *(const bf16x8*)(hbp + (size_t)kb * 4096 + nfl * 128);
            acc4[nfl] = __builtin_amdgcn_mfma_f32_16x16x32_bf16(av, bv, acc4[nfl], 0, 0, 0);
        }
    }

    #pragma unroll
    for (int nfl = 0; nfl < 4; ++nfl) {
        int colg = h * 128 + (sub * 4 + nfl) * 16 + l15;
        float bvv = bias[colg];
        #pragma unroll
        for (int reg = 0; reg < 4; ++reg) {
            int i = g * 4 + reg;                        // D row
            float rin = is_s[h][i];
            out[(size_t)(b * NN + i0 + i) * HD + colg] = acc4[nfl][reg] * rin + bvv;
        }
    }
}

extern "C" void kernel_launch(void* const* d_in, const int* in_sizes, int n_in,
                              void* d_out, int out_size, void* d_ws, size_t ws_size,
                              hipStream_t stream)
{
    const float* x    = (const float*)d_in[0];
    const float* adj  = (const float*)d_in[1];
    const float* w    = (const float*)d_in[2];
    const float* ai   = (const float*)d_in[3];
    const float* aj   = (const float*)d_in[4];
    const float* bias = (const float*)d_in[5];
    float* out = (float*)d_out;

    char* ws = (char*)d_ws;
    unsigned short* xb = (unsigned short*)ws;                       // 8,388,608 B
    unsigned short* wB = (unsigned short*)(ws + 8388608);           //   262,144 B
    unsigned short* hB = (unsigned short*)(ws + 8650752);           // 16,777,216 B
    float* ci          = (float*)(ws + 25427968);                   //   262,144 B
    float* cj          = (float*)(ws + 25690112);                   //   262,144 B

    kpack_x<<<2048, 256, 0, stream>>>(x, xb);
    kpack_w<<<512, 256, 0, stream>>>(w, wB);
    k_proj<<<BSZ * NN / 32, 256, 0, stream>>>(xb, wB, ai, aj, hB, ci, cj);
    k_attn<<<BSZ * (NN / 16), 512, 0, stream>>>(adj, hB, ci, cj, bias, out);
}